// Round 1
// baseline (210.456 us; speedup 1.0000x reference)
//
#include <hip/hip_runtime.h>
#include <hip/hip_bf16.h>

// MHA fused: B=2, S=2048, D=1024, H=16, Dh=64.  bf16 MFMA pipeline.
#define SEQ   2048
#define NH    16
#define HD    64
#define DM    1024
#define MROWS 4096   // B*S

typedef __attribute__((ext_vector_type(4))) float f32x4;
typedef __attribute__((ext_vector_type(8))) short s16x8;
typedef __attribute__((ext_vector_type(4))) short s16x4;

__device__ __forceinline__ short f2bf(float f) {
  union { float f; unsigned u; } v; v.f = f;
  return (short)((v.u + 0x7fff + ((v.u >> 16) & 1)) >> 16);
}

__device__ __forceinline__ void gload_lds16(const short* g, short* l) {
  __builtin_amdgcn_global_load_lds(
      (const __attribute__((address_space(1))) void*)g,
      (__attribute__((address_space(3))) void*)l, 16, 0, 0);
}

// ---------------- fp32 -> bf16 cast of x ----------------
__global__ void cvt_x(const float* __restrict__ x, short* __restrict__ xb) {
  int i = (blockIdx.x * 256 + threadIdx.x) * 8;
  const float4* p = reinterpret_cast<const float4*>(x + i);
  float4 a = p[0], b = p[1];
  s16x8 o;
  o[0] = f2bf(a.x); o[1] = f2bf(a.y); o[2] = f2bf(a.z); o[3] = f2bf(a.w);
  o[4] = f2bf(b.x); o[5] = f2bf(b.y); o[6] = f2bf(b.z); o[7] = f2bf(b.w);
  *reinterpret_cast<s16x8*>(xb + i) = o;
}

// ------------- weight transpose+cast: W[k][n] fp32 -> WT[n][k] bf16 -------------
__global__ void wtrans(const float* __restrict__ Wq, const float* __restrict__ Wk,
                       const float* __restrict__ Wv, const float* __restrict__ Wo,
                       short* __restrict__ WT) {
  __shared__ float tile[64][65];
  const float* W = (blockIdx.z == 0) ? Wq : (blockIdx.z == 1) ? Wk : (blockIdx.z == 2) ? Wv : Wo;
  short* dst = WT + (size_t)blockIdx.z * DM * DM;
  int kbase = blockIdx.x * 64;   // input-dim rows of W
  int nbase = blockIdx.y * 64;   // output-dim cols of W
  int t = threadIdx.x;
  {
    int n4 = (t & 15) * 4;
    #pragma unroll
    for (int rr = 0; rr < 4; ++rr) {
      int r = (t >> 4) + 16 * rr;
      float4 v = *reinterpret_cast<const float4*>(W + (size_t)(kbase + r) * DM + nbase + n4);
      tile[r][n4] = v.x; tile[r][n4 + 1] = v.y; tile[r][n4 + 2] = v.z; tile[r][n4 + 3] = v.w;
    }
  }
  __syncthreads();
  {
    int n = t >> 2, kc = (t & 3) * 16;
    short tmp[16];
    #pragma unroll
    for (int j = 0; j < 16; ++j) tmp[j] = f2bf(tile[kc + j][n]);
    s16x8* q = reinterpret_cast<s16x8*>(dst + (size_t)(nbase + n) * DM + kbase + kc);
    q[0] = *reinterpret_cast<s16x8*>(tmp);
    q[1] = *reinterpret_cast<s16x8*>(tmp + 8);
  }
}

// ------------- V transpose: V[bh][s][64] -> Vt[bh][64][s] (bf16) -------------
__global__ void vtrans(const short* __restrict__ V, short* __restrict__ Vt) {
  __shared__ __align__(16) short tile[64][72];
  int bh = blockIdx.y, sbase = blockIdx.x * 64;
  int t = threadIdx.x;
  {
    int s = t >> 2, dc = (t & 3) * 16;
    const s16x8* p = reinterpret_cast<const s16x8*>(V + ((size_t)bh * SEQ + sbase + s) * HD + dc);
    *reinterpret_cast<s16x8*>(&tile[s][dc]) = p[0];
    *reinterpret_cast<s16x8*>(&tile[s][dc + 8]) = p[1];
  }
  __syncthreads();
  {
    int d = t >> 2, sc = (t & 3) * 16;
    short tmp[16];
    #pragma unroll
    for (int j = 0; j < 16; ++j) tmp[j] = tile[sc + j][d];
    s16x8* q = reinterpret_cast<s16x8*>(Vt + ((size_t)bh * HD + d) * SEQ + sbase + sc);
    q[0] = *reinterpret_cast<s16x8*>(tmp);
    q[1] = *reinterpret_cast<s16x8*>(tmp + 8);
  }
}

// ------------- GEMM: C[M,N] = A[M,K=1024] @ BT[N,K]^T (+bias)  -------------
// EPI==0: QKV epilogue (bf16 out, bias, Q scaled 0.125, [B,H,S,64] layout)
// EPI==1: fp32 out + bias to oF [M][1024]
template<int EPI>
__global__ __launch_bounds__(256, 2) void gemm_bt(
    const short* __restrict__ A, const short* __restrict__ BT,
    const float* __restrict__ bias0, const float* __restrict__ bias1,
    const float* __restrict__ bias2,
    short* __restrict__ oQ, short* __restrict__ oK, short* __restrict__ oV,
    float* __restrict__ oF) {
  __shared__ __align__(16) short As[128 * 64];
  __shared__ __align__(16) short Bs[128 * 64];
  const int lane = threadIdx.x & 63;
  const int wid = threadIdx.x >> 6;
  const int mbase = blockIdx.x * 128;
  const int nbase = blockIdx.y * 128;
  const int wm = wid >> 1, wn = wid & 1;

  f32x4 acc[4][4] = {};
  const int srow = lane >> 3;
  const int skk = (lane & 7) * 8;

  for (int k0 = 0; k0 < DM; k0 += 64) {
    #pragma unroll
    for (int j = 0; j < 4; ++j) {
      int c = wid * 4 + j;
      int row = c * 8 + srow;
      gload_lds16(A + (size_t)(mbase + row) * DM + k0 + skk, As + c * 512);
      gload_lds16(BT + (size_t)(nbase + row) * DM + k0 + skk, Bs + c * 512);
    }
    __syncthreads();
    #pragma unroll
    for (int ks = 0; ks < 2; ++ks) {
      s16x8 af[4], bfr[4];
      #pragma unroll
      for (int m = 0; m < 4; ++m)
        af[m] = *reinterpret_cast<const s16x8*>(
            As + (wm * 64 + m * 16 + (lane & 15)) * 64 + ks * 32 + (lane >> 4) * 8);
      #pragma unroll
      for (int n = 0; n < 4; ++n)
        bfr[n] = *reinterpret_cast<const s16x8*>(
            Bs + (wn * 64 + n * 16 + (lane & 15)) * 64 + ks * 32 + (lane >> 4) * 8);
      #pragma unroll
      for (int m = 0; m < 4; ++m)
        #pragma unroll
        for (int n = 0; n < 4; ++n)
          acc[m][n] = __builtin_amdgcn_mfma_f32_16x16x32_bf16(af[m], bfr[n], acc[m][n], 0, 0, 0);
    }
    __syncthreads();
  }

  const int r0 = mbase + wm * 64;
  const int c0 = nbase + wn * 64;
  #pragma unroll
  for (int m = 0; m < 4; ++m) {
    #pragma unroll
    for (int n = 0; n < 4; ++n) {
      int rr = r0 + m * 16 + ((lane >> 4) << 2);
      int cc = c0 + n * 16 + (lane & 15);
      #pragma unroll
      for (int i = 0; i < 4; ++i) {
        int r = rr + i;
        float v = acc[m][n][i];
        if (EPI == 0) {
          int seg = cc >> 10, c1 = cc & 1023;
          const float* bp = (seg == 0) ? bias0 : (seg == 1) ? bias1 : bias2;
          v += bp[c1];
          if (seg == 0) v *= 0.125f;  // fold attention scale into Q
          int h = c1 >> 6, d = c1 & 63;
          int b = r >> 11, s = r & 2047;
          size_t idx = (((size_t)(b * NH + h) * SEQ + s) << 6) + d;
          short* dst = (seg == 0) ? oQ : (seg == 1) ? oK : oV;
          dst[idx] = f2bf(v);
        } else {
          v += bias0[cc];
          oF[(size_t)r * DM + cc] = v;
        }
      }
    }
  }
}

// ------------- flash attention: Q,K [bh][s][64], Vt [bh][64][s] -> ctx [B][S][1024] -------------
__global__ __launch_bounds__(256, 2) void attn(const short* __restrict__ Q,
                                               const short* __restrict__ K,
                                               const short* __restrict__ Vt,
                                               short* __restrict__ ctx) {
  const int bh = blockIdx.y;
  const int lane = threadIdx.x & 63;
  const int wid = threadIdx.x >> 6;
  const int qbase = blockIdx.x * 128 + wid * 32;
  const short* Qh = Q + (size_t)bh * SEQ * HD;
  const short* Kh = K + (size_t)bh * SEQ * HD;
  const short* Vh = Vt + (size_t)bh * HD * SEQ;

  __shared__ __align__(16) short Plds[4][32][72];
  short(*P)[72] = Plds[wid];

  // Q fragments (held in registers for the whole kv loop); Q pre-scaled by 0.125
  s16x8 qf[2][2];
  #pragma unroll
  for (int qb = 0; qb < 2; ++qb)
    #pragma unroll
    for (int ks = 0; ks < 2; ++ks)
      qf[qb][ks] = *reinterpret_cast<const s16x8*>(
          Qh + (size_t)(qbase + qb * 16 + (lane & 15)) * HD + ks * 32 + (lane >> 4) * 8);

  f32x4 acco[2][4] = {};          // [qb][dvb] : ctx^T fragments
  float mrun[2] = {-1e30f, -1e30f};
  float lrun[2] = {0.f, 0.f};

  for (int kv0 = 0; kv0 < SEQ; kv0 += 64) {
    // ---- S^T = K @ Q^T : D rows = kv, cols = q ----
    f32x4 sacc[2][4] = {};        // [qb][kb]
    #pragma unroll
    for (int kb = 0; kb < 4; ++kb) {
      s16x8 kf0 = *reinterpret_cast<const s16x8*>(
          Kh + (size_t)(kv0 + kb * 16 + (lane & 15)) * HD + (lane >> 4) * 8);
      s16x8 kf1 = *reinterpret_cast<const s16x8*>(
          Kh + (size_t)(kv0 + kb * 16 + (lane & 15)) * HD + 32 + (lane >> 4) * 8);
      #pragma unroll
      for (int qb = 0; qb < 2; ++qb) {
        sacc[qb][kb] = __builtin_amdgcn_mfma_f32_16x16x32_bf16(kf0, qf[qb][0], sacc[qb][kb], 0, 0, 0);
        sacc[qb][kb] = __builtin_amdgcn_mfma_f32_16x16x32_bf16(kf1, qf[qb][1], sacc[qb][kb], 0, 0, 0);
      }
    }
    // ---- online softmax (per q = lane&15, replicated over lane groups) ----
    #pragma unroll
    for (int qb = 0; qb < 2; ++qb) {
      float tmax = -1e30f;
      #pragma unroll
      for (int kb = 0; kb < 4; ++kb)
        #pragma unroll
        for (int i = 0; i < 4; ++i) tmax = fmaxf(tmax, sacc[qb][kb][i]);
      tmax = fmaxf(tmax, __shfl_xor(tmax, 16));
      tmax = fmaxf(tmax, __shfl_xor(tmax, 32));
      float mnew = fmaxf(mrun[qb], tmax);
      float r = __expf(mrun[qb] - mnew);
      float psum = 0.f;
      #pragma unroll
      for (int kb = 0; kb < 4; ++kb) {
        s16x4 pk;
        #pragma unroll
        for (int i = 0; i < 4; ++i) {
          float p = __expf(sacc[qb][kb][i] - mnew);
          psum += p;
          pk[i] = f2bf(p);
        }
        *reinterpret_cast<s16x4*>(&P[qb * 16 + (lane & 15)][kb * 16 + (lane >> 4) * 4]) = pk;
      }
      psum += __shfl_xor(psum, 16);
      psum += __shfl_xor(psum, 32);
      lrun[qb] = lrun[qb] * r + psum;
      mrun[qb] = mnew;
      #pragma unroll
      for (int dvb = 0; dvb < 4; ++dvb) acco[qb][dvb] *= r;
    }
    // ---- ctx^T += V^T @ P^T ----
    s16x8 pf[2][2];
    #pragma unroll
    for (int qb = 0; qb < 2; ++qb)
      #pragma unroll
      for (int ks = 0; ks < 2; ++ks)
        pf[qb][ks] = *reinterpret_cast<const s16x8*>(
            &P[qb * 16 + (lane & 15)][ks * 32 + (lane >> 4) * 8]);
    #pragma unroll
    for (int dvb = 0; dvb < 4; ++dvb) {
      s16x8 vf0 = *reinterpret_cast<const s16x8*>(
          Vh + (size_t)(dvb * 16 + (lane & 15)) * SEQ + kv0 + (lane >> 4) * 8);
      s16x8 vf1 = *reinterpret_cast<const s16x8*>(
          Vh + (size_t)(dvb * 16 + (lane & 15)) * SEQ + kv0 + 32 + (lane >> 4) * 8);
      #pragma unroll
      for (int qb = 0; qb < 2; ++qb) {
        acco[qb][dvb] = __builtin_amdgcn_mfma_f32_16x16x32_bf16(vf0, pf[qb][0], acco[qb][dvb], 0, 0, 0);
        acco[qb][dvb] = __builtin_amdgcn_mfma_f32_16x16x32_bf16(vf1, pf[qb][1], acco[qb][dvb], 0, 0, 0);
      }
    }
  }

  // ---- epilogue: ctx[b][s][h*64+d] = acco / l ----
  const int b = bh >> 4, h = bh & 15;
  #pragma unroll
  for (int qb = 0; qb < 2; ++qb) {
    float inv = 1.f / lrun[qb];
    int q = qbase + qb * 16 + (lane & 15);
    #pragma unroll
    for (int dvb = 0; dvb < 4; ++dvb) {
      s16x4 o;
      #pragma unroll
      for (int i = 0; i < 4; ++i) o[i] = f2bf(acco[qb][dvb][i] * inv);
      int d = dvb * 16 + ((lane >> 4) << 2);
      *reinterpret_cast<s16x4*>(ctx + ((size_t)b * SEQ + q) * DM + h * HD + d) = o;
    }
  }
}

extern "C" void kernel_launch(void* const* d_in, const int* in_sizes, int n_in,
                              void* d_out, int out_size, void* d_ws, size_t ws_size,
                              hipStream_t stream) {
  const float* x = (const float*)d_in[0];
  const float* Wq = (const float*)d_in[1];
  const float* bq = (const float*)d_in[2];
  const float* Wk = (const float*)d_in[3];
  const float* bk = (const float*)d_in[4];
  const float* Wv = (const float*)d_in[5];
  const float* bv = (const float*)d_in[6];
  const float* Wo = (const float*)d_in[7];
  const float* bo = (const float*)d_in[8];

  char* ws = (char*)d_ws;
  const size_t MB8 = (size_t)8 << 20;
  short* xb  = (short*)(ws);
  short* WT  = (short*)(ws + 1 * MB8);  // rows 0..1023 Wq^T, 1024.. Wk^T, 2048.. Wv^T, 3072.. Wo^T
  short* Qb  = (short*)(ws + 2 * MB8);  // [B,H,S,64]
  short* Kb  = (short*)(ws + 3 * MB8);
  short* Vb  = (short*)(ws + 4 * MB8);
  short* Vtb = (short*)(ws + 5 * MB8);  // [B,H,64,S]
  short* ctx = (short*)(ws + 6 * MB8);  // [B,S,1024]

  cvt_x<<<dim3(MROWS * DM / 2048), 256, 0, stream>>>(x, xb);
  wtrans<<<dim3(16, 16, 4), 256, 0, stream>>>(Wq, Wk, Wv, Wo, WT);
  gemm_bt<0><<<dim3(32, 24), 256, 0, stream>>>(xb, WT, bq, bk, bv, Qb, Kb, Vb, nullptr);
  vtrans<<<dim3(SEQ / 64, 32), 256, 0, stream>>>(Vb, Vtb);
  attn<<<dim3(SEQ / 128, 32), 256, 0, stream>>>(Qb, Kb, Vtb, ctx);
  gemm_bt<1><<<dim3(32, 8), 256, 0, stream>>>(ctx, WT + (size_t)3072 * DM, bo, nullptr, nullptr,
                                              nullptr, nullptr, nullptr, (float*)d_out);
}

// Round 2
// 144.312 us; speedup vs baseline: 1.4583x; 1.4583x over previous
//
#include <hip/hip_runtime.h>
#include <hip/hip_bf16.h>

// MHA fused: B=2, S=2048, D=1024, H=16, Dh=64.  bf16 MFMA pipeline.
#define SEQ   2048
#define NH    16
#define HD    64
#define DM    1024
#define MROWS 4096   // B*S

typedef __attribute__((ext_vector_type(4))) float f32x4;
typedef __attribute__((ext_vector_type(8))) short s16x8;
typedef __attribute__((ext_vector_type(4))) short s16x4;

__device__ __forceinline__ short f2bf(float f) {
  union { float f; unsigned u; } v; v.f = f;
  return (short)((v.u + 0x7fff + ((v.u >> 16) & 1)) >> 16);
}

__device__ __forceinline__ void gload_lds16(const short* g, short* l) {
  __builtin_amdgcn_global_load_lds(
      (const __attribute__((address_space(1))) void*)g,
      (__attribute__((address_space(3))) void*)l, 16, 0, 0);
}

// ---------------- fp32 -> bf16 cast of x ----------------
__global__ void cvt_x(const float* __restrict__ x, short* __restrict__ xb) {
  int i = (blockIdx.x * 256 + threadIdx.x) * 8;
  const float4* p = reinterpret_cast<const float4*>(x + i);
  float4 a = p[0], b = p[1];
  s16x8 o;
  o[0] = f2bf(a.x); o[1] = f2bf(a.y); o[2] = f2bf(a.z); o[3] = f2bf(a.w);
  o[4] = f2bf(b.x); o[5] = f2bf(b.y); o[6] = f2bf(b.z); o[7] = f2bf(b.w);
  *reinterpret_cast<s16x8*>(xb + i) = o;
}

// ------------- weight transpose+cast: W[k][n] fp32 -> WT[n][k] bf16 -------------
__global__ void wtrans(const float* __restrict__ Wq, const float* __restrict__ Wk,
                       const float* __restrict__ Wv, const float* __restrict__ Wo,
                       short* __restrict__ WT) {
  __shared__ float tile[64][65];
  const float* W = (blockIdx.z == 0) ? Wq : (blockIdx.z == 1) ? Wk : (blockIdx.z == 2) ? Wv : Wo;
  short* dst = WT + (size_t)blockIdx.z * DM * DM;
  int kbase = blockIdx.x * 64;   // input-dim rows of W
  int nbase = blockIdx.y * 64;   // output-dim cols of W
  int t = threadIdx.x;
  {
    int n4 = (t & 15) * 4;
    #pragma unroll
    for (int rr = 0; rr < 4; ++rr) {
      int r = (t >> 4) + 16 * rr;
      float4 v = *reinterpret_cast<const float4*>(W + (size_t)(kbase + r) * DM + nbase + n4);
      tile[r][n4] = v.x; tile[r][n4 + 1] = v.y; tile[r][n4 + 2] = v.z; tile[r][n4 + 3] = v.w;
    }
  }
  __syncthreads();
  {
    int n = t >> 2, kc = (t & 3) * 16;
    short tmp[16];
    #pragma unroll
    for (int j = 0; j < 16; ++j) tmp[j] = f2bf(tile[kc + j][n]);
    s16x8* q = reinterpret_cast<s16x8*>(dst + (size_t)(nbase + n) * DM + kbase + kc);
    q[0] = *reinterpret_cast<s16x8*>(tmp);
    q[1] = *reinterpret_cast<s16x8*>(tmp + 8);
  }
}

// ------------- V transpose: V[bh][s][64] -> Vt[bh][64][s] (bf16) -------------
__global__ void vtrans(const short* __restrict__ V, short* __restrict__ Vt) {
  __shared__ __align__(16) short tile[64][72];
  int bh = blockIdx.y, sbase = blockIdx.x * 64;
  int t = threadIdx.x;
  {
    int s = t >> 2, dc = (t & 3) * 16;
    const s16x8* p = reinterpret_cast<const s16x8*>(V + ((size_t)bh * SEQ + sbase + s) * HD + dc);
    *reinterpret_cast<s16x8*>(&tile[s][dc]) = p[0];
    *reinterpret_cast<s16x8*>(&tile[s][dc + 8]) = p[1];
  }
  __syncthreads();
  {
    int d = t >> 2, sc = (t & 3) * 16;
    short tmp[16];
    #pragma unroll
    for (int j = 0; j < 16; ++j) tmp[j] = tile[sc + j][d];
    s16x8* q = reinterpret_cast<s16x8*>(Vt + ((size_t)bh * HD + d) * SEQ + sbase + sc);
    q[0] = *reinterpret_cast<s16x8*>(tmp);
    q[1] = *reinterpret_cast<s16x8*>(tmp + 8);
  }
}

// ------------- GEMM: C[M,N] = A[M,K=1024] @ BT[N,K]^T (+bias)  -------------
// EPI==0: QKV epilogue (bf16 out, bias, Q scaled 0.125, [B,H,S,64] layout)
// EPI==1: fp32 out + bias to oF [M][1024]
template<int EPI>
__global__ __launch_bounds__(256, 2) void gemm_bt(
    const short* __restrict__ A, const short* __restrict__ BT,
    const float* __restrict__ bias0, const float* __restrict__ bias1,
    const float* __restrict__ bias2,
    short* __restrict__ oQ, short* __restrict__ oK, short* __restrict__ oV,
    float* __restrict__ oF) {
  __shared__ __align__(16) short As[128 * 64];
  __shared__ __align__(16) short Bs[128 * 64];
  const int lane = threadIdx.x & 63;
  const int wid = threadIdx.x >> 6;
  const int mbase = blockIdx.x * 128;
  const int nbase = blockIdx.y * 128;
  const int wm = wid >> 1, wn = wid & 1;

  f32x4 acc[4][4] = {};
  const int srow = lane >> 3;
  const int skk = (lane & 7) * 8;

  for (int k0 = 0; k0 < DM; k0 += 64) {
    #pragma unroll
    for (int j = 0; j < 4; ++j) {
      int c = wid * 4 + j;
      int row = c * 8 + srow;
      gload_lds16(A + (size_t)(mbase + row) * DM + k0 + skk, As + c * 512);
      gload_lds16(BT + (size_t)(nbase + row) * DM + k0 + skk, Bs + c * 512);
    }
    __syncthreads();
    #pragma unroll
    for (int ks = 0; ks < 2; ++ks) {
      s16x8 af[4], bfr[4];
      #pragma unroll
      for (int m = 0; m < 4; ++m)
        af[m] = *reinterpret_cast<const s16x8*>(
            As + (wm * 64 + m * 16 + (lane & 15)) * 64 + ks * 32 + (lane >> 4) * 8);
      #pragma unroll
      for (int n = 0; n < 4; ++n)
        bfr[n] = *reinterpret_cast<const s16x8*>(
            Bs + (wn * 64 + n * 16 + (lane & 15)) * 64 + ks * 32 + (lane >> 4) * 8);
      #pragma unroll
      for (int m = 0; m < 4; ++m)
        #pragma unroll
        for (int n = 0; n < 4; ++n)
          acc[m][n] = __builtin_amdgcn_mfma_f32_16x16x32_bf16(af[m], bfr[n], acc[m][n], 0, 0, 0);
    }
    __syncthreads();
  }

  const int r0 = mbase + wm * 64;
  const int c0 = nbase + wn * 64;
  #pragma unroll
  for (int m = 0; m < 4; ++m) {
    #pragma unroll
    for (int n = 0; n < 4; ++n) {
      int rr = r0 + m * 16 + ((lane >> 4) << 2);
      int cc = c0 + n * 16 + (lane & 15);
      #pragma unroll
      for (int i = 0; i < 4; ++i) {
        int r = rr + i;
        float v = acc[m][n][i];
        if (EPI == 0) {
          int seg = cc >> 10, c1 = cc & 1023;
          const float* bp = (seg == 0) ? bias0 : (seg == 1) ? bias1 : bias2;
          v += bp[c1];
          if (seg == 0) v *= 0.125f;  // fold attention scale into Q
          int h = c1 >> 6, d = c1 & 63;
          int b = r >> 11, s = r & 2047;
          size_t idx = (((size_t)(b * NH + h) * SEQ + s) << 6) + d;
          short* dst = (seg == 0) ? oQ : (seg == 1) ? oK : oV;
          dst[idx] = f2bf(v);
        } else {
          v += bias0[cc];
          oF[(size_t)r * DM + cc] = v;
        }
      }
    }
  }
}

// ------------- flash attention v2 -------------
// 8 waves x 16 q-rows = 128 q rows per block.  K,V tiles (64x64 bf16) staged in
// LDS, double-buffered, loaded via global_load_lds with both-sides XOR swizzle
// (granule ^= row&7) so ds_read_b128 at row-stride 128B is conflict-free.
// Q,K [bh][s][64]; Vt [bh][64][s]; ctx [B][S][1024].
#define SWZ(row, gg) ((((row) << 3) + (((gg) ^ ((row) & 7)))) << 3)

__global__ __launch_bounds__(512, 4) void attn(const short* __restrict__ Q,
                                               const short* __restrict__ K,
                                               const short* __restrict__ Vt,
                                               short* __restrict__ ctx) {
  const int bh = blockIdx.y;
  const int lane = threadIdx.x & 63;
  const int wid = threadIdx.x >> 6;          // 0..7
  const int q15 = lane & 15, g4 = lane >> 4;
  const int qrow = blockIdx.x * 128 + wid * 16;
  const short* Qh = Q + (size_t)bh * SEQ * HD;
  const short* Kh = K + (size_t)bh * SEQ * HD;
  const short* Vh = Vt + (size_t)bh * HD * SEQ;

  __shared__ __align__(16) short Ks[2][64 * 64];
  __shared__ __align__(16) short Vs[2][64 * 64];
  __shared__ __align__(16) short Plds[8][16][72];
  short(*P)[72] = Plds[wid];

  // ---- staging addresses: thread t fills LDS bytes [t*16, t*16+16) of each tile.
  // dest row = t>>3, dest granule = t&7 -> source granule (t&7) ^ (row&7).
  const int t = threadIdx.x;
  const int srow = t >> 3;
  const int sg = (t & 7) ^ (srow & 7);
  const short* ksrc = Kh + (size_t)srow * HD + sg * 8;
  const short* vsrc = Vh + (size_t)srow * SEQ + sg * 8;

  // ---- Q fragments in registers (pre-scaled by 0.125 in the GEMM epilogue)
  s16x8 qf[2];
  #pragma unroll
  for (int ks = 0; ks < 2; ++ks)
    qf[ks] = *reinterpret_cast<const s16x8*>(
        Qh + (size_t)(qrow + q15) * HD + ks * 32 + g4 * 8);

  f32x4 acco[4] = {};   // ctx^T fragments [dvb]
  float mrun = -1e30f, lrun = 0.f;

  // prologue: stage tile 0 into buffer 0
  gload_lds16(ksrc, Ks[0] + wid * 512);
  gload_lds16(vsrc, Vs[0] + wid * 512);
  __syncthreads();

  int cur = 0;
  for (int kv0 = 0; kv0 < SEQ; kv0 += 64) {
    // issue prefetch of next tile into the other buffer (drained by the
    // end-of-iteration __syncthreads, which waits vmcnt(0))
    if (kv0 + 64 < SEQ) {
      gload_lds16(ksrc + (size_t)(kv0 + 64) * HD, Ks[cur ^ 1] + wid * 512);
      gload_lds16(vsrc + (kv0 + 64), Vs[cur ^ 1] + wid * 512);
    }

    // ---- S^T = K @ Q^T : rows = kv, cols = q ----
    const short* Kb = Ks[cur];
    f32x4 sacc[4] = {};
    #pragma unroll
    for (int kb = 0; kb < 4; ++kb) {
      s16x8 kf0 = *reinterpret_cast<const s16x8*>(Kb + SWZ(kb * 16 + q15, g4));
      s16x8 kf1 = *reinterpret_cast<const s16x8*>(Kb + SWZ(kb * 16 + q15, g4 + 4));
      sacc[kb] = __builtin_amdgcn_mfma_f32_16x16x32_bf16(kf0, qf[0], sacc[kb], 0, 0, 0);
      sacc[kb] = __builtin_amdgcn_mfma_f32_16x16x32_bf16(kf1, qf[1], sacc[kb], 0, 0, 0);
    }

    // ---- online softmax (per q = lane&15, replicated over 4 lane groups) ----
    float tmax = -1e30f;
    #pragma unroll
    for (int kb = 0; kb < 4; ++kb)
      #pragma unroll
      for (int i = 0; i < 4; ++i) tmax = fmaxf(tmax, sacc[kb][i]);
    tmax = fmaxf(tmax, __shfl_xor(tmax, 16));
    tmax = fmaxf(tmax, __shfl_xor(tmax, 32));
    float mnew = fmaxf(mrun, tmax);
    float r = __expf(mrun - mnew);
    float psum = 0.f;
    #pragma unroll
    for (int kb = 0; kb < 4; ++kb) {
      s16x4 pk;
      #pragma unroll
      for (int i = 0; i < 4; ++i) {
        float p = __expf(sacc[kb][i] - mnew);
        psum += p;
        pk[i] = f2bf(p);
      }
      *reinterpret_cast<s16x4*>(&P[q15][kb * 16 + g4 * 4]) = pk;
    }
    psum += __shfl_xor(psum, 16);
    psum += __shfl_xor(psum, 32);
    lrun = lrun * r + psum;
    mrun = mnew;
    #pragma unroll
    for (int dvb = 0; dvb < 4; ++dvb) acco[dvb] *= r;

    // ---- ctx^T += V^T @ P^T ----  (P row q15 written by all 4 lane groups;
    // wave-synchronous LDS ordering makes the cross-lane read safe)
    s16x8 pf0 = *reinterpret_cast<const s16x8*>(&P[q15][g4 * 8]);
    s16x8 pf1 = *reinterpret_cast<const s16x8*>(&P[q15][32 + g4 * 8]);
    const short* Vb = Vs[cur];
    #pragma unroll
    for (int dvb = 0; dvb < 4; ++dvb) {
      s16x8 vf0 = *reinterpret_cast<const s16x8*>(Vb + SWZ(dvb * 16 + q15, g4));
      s16x8 vf1 = *reinterpret_cast<const s16x8*>(Vb + SWZ(dvb * 16 + q15, g4 + 4));
      acco[dvb] = __builtin_amdgcn_mfma_f32_16x16x32_bf16(vf0, pf0, acco[dvb], 0, 0, 0);
      acco[dvb] = __builtin_amdgcn_mfma_f32_16x16x32_bf16(vf1, pf1, acco[dvb], 0, 0, 0);
    }

    __syncthreads();   // drains vmcnt (prefetch) + lgkm; buffers swap safely
    cur ^= 1;
  }

  // ---- epilogue: ctx[b][q][h*64+d] = acco / l ----
  const int b = bh >> 4, h = bh & 15;
  float inv = 1.f / lrun;
  int q = qrow + q15;
  #pragma unroll
  for (int dvb = 0; dvb < 4; ++dvb) {
    s16x4 o;
    #pragma unroll
    for (int i = 0; i < 4; ++i) o[i] = f2bf(acco[dvb][i] * inv);
    int d = dvb * 16 + g4 * 4;
    *reinterpret_cast<s16x4*>(ctx + ((size_t)b * SEQ + q) * DM + h * HD + d) = o;
  }
}

extern "C" void kernel_launch(void* const* d_in, const int* in_sizes, int n_in,
                              void* d_out, int out_size, void* d_ws, size_t ws_size,
                              hipStream_t stream) {
  const float* x = (const float*)d_in[0];
  const float* Wq = (const float*)d_in[1];
  const float* bq = (const float*)d_in[2];
  const float* Wk = (const float*)d_in[3];
  const float* bk = (const float*)d_in[4];
  const float* Wv = (const float*)d_in[5];
  const float* bv = (const float*)d_in[6];
  const float* Wo = (const float*)d_in[7];
  const float* bo = (const float*)d_in[8];

  char* ws = (char*)d_ws;
  const size_t MB8 = (size_t)8 << 20;
  short* xb  = (short*)(ws);
  short* WT  = (short*)(ws + 1 * MB8);  // rows 0..1023 Wq^T, 1024.. Wk^T, 2048.. Wv^T, 3072.. Wo^T
  short* Qb  = (short*)(ws + 2 * MB8);  // [B,H,S,64]
  short* Kb  = (short*)(ws + 3 * MB8);
  short* Vb  = (short*)(ws + 4 * MB8);
  short* Vtb = (short*)(ws + 5 * MB8);  // [B,H,64,S]
  short* ctx = (short*)(ws + 6 * MB8);  // [B,S,1024]

  cvt_x<<<dim3(MROWS * DM / 2048), 256, 0, stream>>>(x, xb);
  wtrans<<<dim3(16, 16, 4), 256, 0, stream>>>(Wq, Wk, Wv, Wo, WT);
  gemm_bt<0><<<dim3(32, 24), 256, 0, stream>>>(xb, WT, bq, bk, bv, Qb, Kb, Vb, nullptr);
  vtrans<<<dim3(SEQ / 64, 32), 256, 0, stream>>>(Vb, Vtb);
  attn<<<dim3(SEQ / 128, 32), 512, 0, stream>>>(Qb, Kb, Vtb, ctx);
  gemm_bt<1><<<dim3(32, 8), 256, 0, stream>>>(ctx, WT + (size_t)3072 * DM, bo, nullptr, nullptr,
                                              nullptr, nullptr, nullptr, (float*)d_out);
}